// Round 1
// baseline (1201.234 us; speedup 1.0000x reference)
//
#include <hip/hip_runtime.h>
#include <hip/hip_bf16.h>
#include <math.h>
#include <stdint.h>

constexpr int HIDDIM = 64;
constexpr int FEDGE  = 16;
constexpr int SCAN_CHUNK = 1024;

// ---------- c = We @ a_e for both layers (c[0:16]=layer1, c[16:32]=layer2) ----------
__global__ void compute_c_kernel(const float* __restrict__ We1, const float* __restrict__ ae1,
                                 const float* __restrict__ We2, const float* __restrict__ ae2,
                                 float* __restrict__ c) {
  int t = threadIdx.x;
  if (t < FEDGE) {
    float s = 0.f;
    for (int j = 0; j < HIDDIM; ++j) s += We1[t * HIDDIM + j] * ae1[j];
    c[t] = s;
  } else if (t < 2 * FEDGE) {
    int k = t - FEDGE;
    float s = 0.f;
    for (int j = 0; j < HIDDIM; ++j) s += We2[k * HIDDIM + j] * ae2[j];
    c[FEDGE + k] = s;
  }
}

// ---------- degree histogram ----------
__global__ void deg_kernel(const int* __restrict__ dst, int* __restrict__ deg, int E) {
  int e = blockIdx.x * blockDim.x + threadIdx.x;
  if (e < E) atomicAdd(&deg[dst[e]], 1);
}

// ---------- 3-kernel exclusive scan over deg -> offsets ----------
__global__ void chunk_sum_kernel(const int* __restrict__ deg, int* __restrict__ chunkSum, int n) {
  int base = blockIdx.x * SCAN_CHUNK;
  int t = threadIdx.x;             // 256
  int lane = t & 63, wid = t >> 6;
  int s = 0;
#pragma unroll
  for (int k = 0; k < 4; ++k) {
    int i = base + k * 256 + t;
    if (i < n) s += deg[i];
  }
#pragma unroll
  for (int d = 32; d > 0; d >>= 1) s += __shfl_xor(s, d, 64);
  __shared__ int red[4];
  if (lane == 0) red[wid] = s;
  __syncthreads();
  if (t == 0) chunkSum[blockIdx.x] = red[0] + red[1] + red[2] + red[3];
}

__global__ void scan_chunks_kernel(const int* __restrict__ chunkSum, int* __restrict__ chunkOff, int nchunks) {
  __shared__ int s[128];
  int t = threadIdx.x;             // 128
  int v = (t < nchunks) ? chunkSum[t] : 0;
  s[t] = v;
  __syncthreads();
  for (int d = 1; d < 128; d <<= 1) {
    int tv = (t >= d) ? s[t - d] : 0;
    __syncthreads();
    s[t] += tv;
    __syncthreads();
  }
  if (t < nchunks) chunkOff[t] = s[t] - v;   // exclusive
}

__global__ void scan_apply_kernel(const int* __restrict__ deg, const int* __restrict__ chunkOff,
                                  int* __restrict__ offsets, int n, int Etot) {
  int base = blockIdx.x * SCAN_CHUNK;
  int t = threadIdx.x;             // 256
  int lane = t & 63, wid = t >> 6;
  int idx0 = base + t * 4;
  int v[4];
  int s = 0;
#pragma unroll
  for (int k = 0; k < 4; ++k) {
    v[k] = (idx0 + k < n) ? deg[idx0 + k] : 0;
    s += v[k];
  }
  int incl = s;
#pragma unroll
  for (int d = 1; d < 64; d <<= 1) {
    int tv = __shfl_up(incl, d, 64);
    if (lane >= d) incl += tv;
  }
  __shared__ int wsum[4];
  if (lane == 63) wsum[wid] = incl;
  __syncthreads();
  int waveoff = 0;
  for (int w = 0; w < wid; ++w) waveoff += wsum[w];
  int run = incl - s + waveoff + chunkOff[blockIdx.x];
#pragma unroll
  for (int k = 0; k < 4; ++k) {
    if (idx0 + k < n) offsets[idx0 + k] = run;
    run += v[k];
  }
  if (blockIdx.x == 0 && t == 0) offsets[n] = Etot;
}

// ---------- scatter edges into CSR order + per-edge alpha_e scalars (both layers) ----------
__global__ void scatter_kernel(const int* __restrict__ src, const int* __restrict__ dst,
                               const float* __restrict__ attr, const float* __restrict__ c,
                               const int* __restrict__ offsets, int* __restrict__ cursor,
                               int* __restrict__ csr_src, float* __restrict__ a1csr,
                               float* __restrict__ a2csr, int E) {
  int e = blockIdx.x * blockDim.x + threadIdx.x;
  if (e >= E) return;
  int d = dst[e];
  int pos = offsets[d] + atomicAdd(&cursor[d], 1);
  csr_src[pos] = src[e];
  const float4* ap = (const float4*)(attr + (size_t)e * FEDGE);
  float a1 = 0.f, a2 = 0.f;
#pragma unroll
  for (int k = 0; k < 4; ++k) {
    float4 v = ap[k];
    a1 += v.x * c[k*4+0] + v.y * c[k*4+1] + v.z * c[k*4+2] + v.w * c[k*4+3];
    a2 += v.x * c[16+k*4+0] + v.y * c[16+k*4+1] + v.z * c[16+k*4+2] + v.w * c[16+k*4+3];
  }
  a1csr[pos] = a1;
  a2csr[pos] = a2;
}

// ---------- fused h = X @ W, alpha_src = h.a_src, alpha_dst = h.a_dst ----------
__global__ __launch_bounds__(256) void gemm_alpha_kernel(
    const float* __restrict__ X, const float* __restrict__ W,
    const float* __restrict__ a_src, const float* __restrict__ a_dst,
    float* __restrict__ H, float* __restrict__ alpha_s, float* __restrict__ alpha_d, int n) {
  __shared__ float Ws[HIDDIM * HIDDIM];
  __shared__ float as_s[HIDDIM], ad_s[HIDDIM];
  for (int i = threadIdx.x; i < HIDDIM * HIDDIM; i += blockDim.x) Ws[i] = W[i];
  if (threadIdx.x < HIDDIM) {
    as_s[threadIdx.x] = a_src[threadIdx.x];
    ad_s[threadIdx.x] = a_dst[threadIdx.x];
  }
  __syncthreads();
  int lane = threadIdx.x & 63;
  int wid  = threadIdx.x >> 6;
  int wavesTotal = (blockDim.x >> 6) * gridDim.x;
  for (int row = blockIdx.x * (blockDim.x >> 6) + wid; row < n; row += wavesTotal) {
    float xv = X[(size_t)row * HIDDIM + lane];
    float acc = 0.f;
#pragma unroll
    for (int k = 0; k < HIDDIM; ++k) {
      float xk = __shfl(xv, k, 64);
      acc = fmaf(xk, Ws[k * HIDDIM + lane], acc);
    }
    H[(size_t)row * HIDDIM + lane] = acc;
    float s1 = acc * as_s[lane];
    float s2 = acc * ad_s[lane];
#pragma unroll
    for (int d = 32; d > 0; d >>= 1) {
      s1 += __shfl_xor(s1, d, 64);
      s2 += __shfl_xor(s2, d, 64);
    }
    if (lane == 0) {
      alpha_s[row] = s1;
      alpha_d[row] = s2;
    }
  }
}

// ---------- per-node softmax + weighted aggregation (one wave per node) ----------
template <bool FINAL>
__global__ __launch_bounds__(256) void aggregate_kernel(
    const float* __restrict__ H, const float* __restrict__ alpha_s, const float* __restrict__ alpha_d,
    const float* __restrict__ ae_csr, const int* __restrict__ csr_src, const int* __restrict__ offsets,
    const float* __restrict__ bias, const float* __restrict__ fc_w, const float* __restrict__ fc_b,
    float* __restrict__ out, int n) {
  int lane = threadIdx.x & 63;
  int wid  = threadIdx.x >> 6;
  int node = blockIdx.x * (blockDim.x >> 6) + wid;
  if (node >= n) return;
  int off = offsets[node];
  int end = offsets[node + 1];
  int deg = end - off;
  float ad  = alpha_d[node];
  float asn = alpha_s[node];

  // pass 1: segment max of leaky_relu logits + sum of alpha_e (for self-loop mean)
  float lmax = -INFINITY, aesum = 0.f;
  for (int i = lane; i < deg; i += 64) {
    int s   = csr_src[off + i];
    float ae = ae_csr[off + i];
    float lg = alpha_s[s] + ad + ae;
    lg = (lg < 0.f) ? 0.2f * lg : lg;
    lmax = fmaxf(lmax, lg);
    aesum += ae;
  }
#pragma unroll
  for (int d = 32; d > 0; d >>= 1) {
    lmax = fmaxf(lmax, __shfl_xor(lmax, d, 64));
    aesum += __shfl_xor(aesum, d, 64);
  }
  float self_ae = (deg > 0) ? aesum / (float)deg : 0.f;
  float slg = asn + ad + self_ae;
  slg = (slg < 0.f) ? 0.2f * slg : slg;
  float m = fmaxf(lmax, slg);

  // pass 2: lane = feature channel; sequential over edges
  float acc = 0.f, denom = 0.f;
  for (int j = 0; j < deg; ++j) {
    int s    = csr_src[off + j];
    float ae = ae_csr[off + j];
    float lg = alpha_s[s] + ad + ae;
    lg = (lg < 0.f) ? 0.2f * lg : lg;
    float ex = __expf(lg - m);
    denom += ex;
    acc = fmaf(ex, H[(size_t)s * HIDDIM + lane], acc);
  }
  {
    float ex = __expf(slg - m);
    denom += ex;
    acc = fmaf(ex, H[(size_t)node * HIDDIM + lane], acc);
  }
  float res = acc / denom + bias[lane];
  res = (res > 0.f) ? res : (__expf(res) - 1.f);  // ELU
  if (!FINAL) {
    out[(size_t)node * HIDDIM + lane] = res;
  } else {
    float s1 = res * fc_w[lane];
#pragma unroll
    for (int d = 32; d > 0; d >>= 1) s1 += __shfl_xor(s1, d, 64);
    if (lane == 0) out[node] = s1 + fc_b[0];
  }
}

extern "C" void kernel_launch(void* const* d_in, const int* in_sizes, int n_in,
                              void* d_out, int out_size, void* d_ws, size_t ws_size,
                              hipStream_t stream) {
  const float* x    = (const float*)d_in[0];
  const int*   ei   = (const int*)d_in[1];
  const float* attr = (const float*)d_in[2];
  const float* W1   = (const float*)d_in[3];
  const float* as1  = (const float*)d_in[4];
  const float* ad1  = (const float*)d_in[5];
  const float* We1  = (const float*)d_in[6];
  const float* ae1  = (const float*)d_in[7];
  const float* b1   = (const float*)d_in[8];
  const float* W2   = (const float*)d_in[9];
  const float* as2  = (const float*)d_in[10];
  const float* ad2  = (const float*)d_in[11];
  const float* We2  = (const float*)d_in[12];
  const float* ae2  = (const float*)d_in[13];
  const float* b2   = (const float*)d_in[14];
  const float* fcw  = (const float*)d_in[15];
  const float* fcb  = (const float*)d_in[16];

  const int N = in_sizes[0] / HIDDIM;       // 100000 (F_NODE == 64)
  const int E = in_sizes[1] / 2;            // 3200000

  // workspace bump allocator (256B aligned)
  char* p = (char*)d_ws;
  auto alloc = [&](size_t bytes) -> void* {
    void* r = (void*)p;
    p += (bytes + 255) & ~(size_t)255;
    return r;
  };
  float* c        = (float*)alloc(32 * sizeof(float));
  int*   deg      = (int*)alloc((size_t)N * 4);
  int*   offsets  = (int*)alloc(((size_t)N + 1) * 4);
  int*   cursor   = (int*)alloc((size_t)N * 4);
  int*   chunkSum = (int*)alloc(128 * 4);
  int*   chunkOff = (int*)alloc(128 * 4);
  int*   csr_src  = (int*)alloc((size_t)E * 4);
  float* a1csr    = (float*)alloc((size_t)E * 4);
  float* a2csr    = (float*)alloc((size_t)E * 4);
  float* alpha_s  = (float*)alloc((size_t)N * 4);
  float* alpha_d  = (float*)alloc((size_t)N * 4);
  float* H        = (float*)alloc((size_t)N * HIDDIM * 4);
  float* X2       = (float*)alloc((size_t)N * HIDDIM * 4);

  const int* srcp = ei;
  const int* dstp = ei + E;

  hipMemsetAsync(deg, 0, (size_t)N * 4, stream);
  hipMemsetAsync(cursor, 0, (size_t)N * 4, stream);

  compute_c_kernel<<<1, 64, 0, stream>>>(We1, ae1, We2, ae2, c);

  int ethreads = 256;
  int eblocks = (E + ethreads - 1) / ethreads;
  deg_kernel<<<eblocks, ethreads, 0, stream>>>(dstp, deg, E);

  int nchunks = (N + SCAN_CHUNK - 1) / SCAN_CHUNK;   // 98
  chunk_sum_kernel<<<nchunks, 256, 0, stream>>>(deg, chunkSum, N);
  scan_chunks_kernel<<<1, 128, 0, stream>>>(chunkSum, chunkOff, nchunks);
  scan_apply_kernel<<<nchunks, 256, 0, stream>>>(deg, chunkOff, offsets, N, E);

  scatter_kernel<<<eblocks, ethreads, 0, stream>>>(srcp, dstp, attr, c, offsets, cursor,
                                                   csr_src, a1csr, a2csr, E);

  int aggBlocks = (N + 3) / 4;   // 4 waves (nodes) per 256-thread block

  // layer 1
  gemm_alpha_kernel<<<2048, 256, 0, stream>>>(x, W1, as1, ad1, H, alpha_s, alpha_d, N);
  aggregate_kernel<false><<<aggBlocks, 256, 0, stream>>>(H, alpha_s, alpha_d, a1csr, csr_src,
                                                         offsets, b1, nullptr, nullptr, X2, N);
  // layer 2 + fused FC
  gemm_alpha_kernel<<<2048, 256, 0, stream>>>(X2, W2, as2, ad2, H, alpha_s, alpha_d, N);
  aggregate_kernel<true><<<aggBlocks, 256, 0, stream>>>(H, alpha_s, alpha_d, a2csr, csr_src,
                                                        offsets, b2, fcw, fcb, (float*)d_out, N);
}

// Round 2
// 726.258 us; speedup vs baseline: 1.6540x; 1.6540x over previous
//
#include <hip/hip_runtime.h>
#include <hip/hip_bf16.h>
#include <math.h>
#include <stdint.h>

constexpr int HIDDIM = 64;
constexpr int FEDGE  = 16;
constexpr int SCAN_CHUNK = 1024;

// ---------- c = We @ a_e for both layers (c[0:16]=layer1, c[16:32]=layer2) ----------
__global__ void compute_c_kernel(const float* __restrict__ We1, const float* __restrict__ ae1,
                                 const float* __restrict__ We2, const float* __restrict__ ae2,
                                 float* __restrict__ c) {
  int t = threadIdx.x;
  if (t < FEDGE) {
    float s = 0.f;
    for (int j = 0; j < HIDDIM; ++j) s += We1[t * HIDDIM + j] * ae1[j];
    c[t] = s;
  } else if (t < 2 * FEDGE) {
    int k = t - FEDGE;
    float s = 0.f;
    for (int j = 0; j < HIDDIM; ++j) s += We2[k * HIDDIM + j] * ae2[j];
    c[FEDGE + k] = s;
  }
}

// ---------- degree histogram ----------
__global__ void deg_kernel(const int* __restrict__ dst, int* __restrict__ deg, int E) {
  int e = blockIdx.x * blockDim.x + threadIdx.x;
  if (e < E) atomicAdd(&deg[dst[e]], 1);
}

// ---------- 3-kernel exclusive scan over deg -> offsets ----------
__global__ void chunk_sum_kernel(const int* __restrict__ deg, int* __restrict__ chunkSum, int n) {
  int base = blockIdx.x * SCAN_CHUNK;
  int t = threadIdx.x;             // 256
  int lane = t & 63, wid = t >> 6;
  int s = 0;
#pragma unroll
  for (int k = 0; k < 4; ++k) {
    int i = base + k * 256 + t;
    if (i < n) s += deg[i];
  }
#pragma unroll
  for (int d = 32; d > 0; d >>= 1) s += __shfl_xor(s, d, 64);
  __shared__ int red[4];
  if (lane == 0) red[wid] = s;
  __syncthreads();
  if (t == 0) chunkSum[blockIdx.x] = red[0] + red[1] + red[2] + red[3];
}

__global__ void scan_chunks_kernel(const int* __restrict__ chunkSum, int* __restrict__ chunkOff, int nchunks) {
  __shared__ int s[128];
  int t = threadIdx.x;             // 128
  int v = (t < nchunks) ? chunkSum[t] : 0;
  s[t] = v;
  __syncthreads();
  for (int d = 1; d < 128; d <<= 1) {
    int tv = (t >= d) ? s[t - d] : 0;
    __syncthreads();
    s[t] += tv;
    __syncthreads();
  }
  if (t < nchunks) chunkOff[t] = s[t] - v;   // exclusive
}

__global__ void scan_apply_kernel(const int* __restrict__ deg, const int* __restrict__ chunkOff,
                                  int* __restrict__ offsets, int n, int Etot) {
  int base = blockIdx.x * SCAN_CHUNK;
  int t = threadIdx.x;             // 256
  int lane = t & 63, wid = t >> 6;
  int idx0 = base + t * 4;
  int v[4];
  int s = 0;
#pragma unroll
  for (int k = 0; k < 4; ++k) {
    v[k] = (idx0 + k < n) ? deg[idx0 + k] : 0;
    s += v[k];
  }
  int incl = s;
#pragma unroll
  for (int d = 1; d < 64; d <<= 1) {
    int tv = __shfl_up(incl, d, 64);
    if (lane >= d) incl += tv;
  }
  __shared__ int wsum[4];
  if (lane == 63) wsum[wid] = incl;
  __syncthreads();
  int waveoff = 0;
  for (int w = 0; w < wid; ++w) waveoff += wsum[w];
  int run = incl - s + waveoff + chunkOff[blockIdx.x];
#pragma unroll
  for (int k = 0; k < 4; ++k) {
    if (idx0 + k < n) offsets[idx0 + k] = run;
    run += v[k];
  }
  if (blockIdx.x == 0 && t == 0) offsets[n] = Etot;
}

// ---------- scatter edges into CSR order: packed {src, a1, a2, pad} per edge ----------
__global__ void scatter_kernel(const int* __restrict__ src, const int* __restrict__ dst,
                               const float* __restrict__ attr, const float* __restrict__ c,
                               const int* __restrict__ offsets, int* __restrict__ cursor,
                               float4* __restrict__ EDG, int E) {
  int e = blockIdx.x * blockDim.x + threadIdx.x;
  if (e >= E) return;
  int d = dst[e];
  int pos = offsets[d] + atomicAdd(&cursor[d], 1);
  const float4* ap = (const float4*)(attr + (size_t)e * FEDGE);
  float a1 = 0.f, a2 = 0.f;
#pragma unroll
  for (int k = 0; k < 4; ++k) {
    float4 v = ap[k];
    a1 += v.x * c[k*4+0] + v.y * c[k*4+1] + v.z * c[k*4+2] + v.w * c[k*4+3];
    a2 += v.x * c[16+k*4+0] + v.y * c[16+k*4+1] + v.z * c[16+k*4+2] + v.w * c[16+k*4+3];
  }
  float4 o;
  o.x = __int_as_float(src[e]);
  o.y = a1;
  o.z = a2;
  o.w = 0.f;
  EDG[pos] = o;
}

// ---------- fused h = X @ W, alpha_src = h.a_src, alpha_dst = h.a_dst ----------
__global__ __launch_bounds__(256) void gemm_alpha_kernel(
    const float* __restrict__ X, const float* __restrict__ W,
    const float* __restrict__ a_src, const float* __restrict__ a_dst,
    float* __restrict__ H, float* __restrict__ alpha_s, float* __restrict__ alpha_d, int n) {
  __shared__ float Ws[HIDDIM * HIDDIM];
  __shared__ float as_s[HIDDIM], ad_s[HIDDIM];
  for (int i = threadIdx.x; i < HIDDIM * HIDDIM; i += blockDim.x) Ws[i] = W[i];
  if (threadIdx.x < HIDDIM) {
    as_s[threadIdx.x] = a_src[threadIdx.x];
    ad_s[threadIdx.x] = a_dst[threadIdx.x];
  }
  __syncthreads();
  int lane = threadIdx.x & 63;
  int wid  = threadIdx.x >> 6;
  int wavesTotal = (blockDim.x >> 6) * gridDim.x;
  for (int row = blockIdx.x * (blockDim.x >> 6) + wid; row < n; row += wavesTotal) {
    float xv = X[(size_t)row * HIDDIM + lane];
    float acc = 0.f;
#pragma unroll
    for (int k = 0; k < HIDDIM; ++k) {
      float xk = __shfl(xv, k, 64);
      acc = fmaf(xk, Ws[k * HIDDIM + lane], acc);
    }
    H[(size_t)row * HIDDIM + lane] = acc;
    float s1 = acc * as_s[lane];
    float s2 = acc * ad_s[lane];
#pragma unroll
    for (int d = 32; d > 0; d >>= 1) {
      s1 += __shfl_xor(s1, d, 64);
      s2 += __shfl_xor(s2, d, 64);
    }
    if (lane == 0) {
      alpha_s[row] = s1;
      alpha_d[row] = s2;
    }
  }
}

__device__ __forceinline__ float leaky(float x) { return (x < 0.f) ? 0.2f * x : x; }

// ---------- per-node softmax + weighted aggregation (one wave per node) ----------
// SEL: 0 -> use a1 (ed.y), 1 -> use a2 (ed.z)
template <bool FINAL, int SEL>
__global__ __launch_bounds__(256) void aggregate_kernel(
    const float* __restrict__ H, const float* __restrict__ alpha_s, const float* __restrict__ alpha_d,
    const float4* __restrict__ EDG, const int* __restrict__ offsets,
    const float* __restrict__ bias, const float* __restrict__ fc_w, const float* __restrict__ fc_b,
    float* __restrict__ out, int n) {
  int lane = threadIdx.x & 63;
  int wid  = threadIdx.x >> 6;
  int node = blockIdx.x * (blockDim.x >> 6) + wid;
  if (node >= n) return;
  int off = offsets[node];
  int deg = offsets[node + 1] - off;
  float ad  = alpha_d[node];
  float asn = alpha_s[node];

  float acc, denom;

  if (deg <= 64) {
    // ---- fast path: whole neighborhood lane-parallel in registers ----
    float4 ed = make_float4(0.f, 0.f, 0.f, 0.f);
    if (lane < deg) ed = EDG[off + lane];
    int   s_l  = __float_as_int(ed.x);          // 0 for inactive lanes
    float ae_l = (SEL == 0) ? ed.y : ed.z;
    float as_g = (lane < deg) ? alpha_s[s_l] : 0.f;   // 64 parallel gathers
    float lg_l = (lane < deg) ? leaky(as_g + ad + ae_l) : -INFINITY;
    float aesum = (lane < deg) ? ae_l : 0.f;
    float lmax = lg_l;
#pragma unroll
    for (int d = 32; d > 0; d >>= 1) {
      lmax = fmaxf(lmax, __shfl_xor(lmax, d, 64));
      aesum += __shfl_xor(aesum, d, 64);
    }
    float self_ae = (deg > 0) ? aesum / (float)deg : 0.f;
    float slg = leaky(asn + ad + self_ae);
    float m = fmaxf(lmax, slg);

    float ex_l = (lane < deg) ? __expf(lg_l - m) : 0.f;
    float dsum = ex_l;
#pragma unroll
    for (int d = 32; d > 0; d >>= 1) dsum += __shfl_xor(dsum, d, 64);
    float exs = __expf(slg - m);
    denom = dsum + exs;

    // self term (coalesced)
    acc = exs * H[(size_t)node * HIDDIM + lane];

    // broadcast loop over edges, 4 gathers in flight
    int j = 0;
    for (; j + 4 <= deg; j += 4) {
      int   s0 = __shfl(s_l, j, 64),   s1 = __shfl(s_l, j + 1, 64);
      int   s2 = __shfl(s_l, j + 2, 64), s3 = __shfl(s_l, j + 3, 64);
      float e0 = __shfl(ex_l, j, 64),  e1 = __shfl(ex_l, j + 1, 64);
      float e2 = __shfl(ex_l, j + 2, 64), e3 = __shfl(ex_l, j + 3, 64);
      float h0 = H[(size_t)s0 * HIDDIM + lane];
      float h1 = H[(size_t)s1 * HIDDIM + lane];
      float h2 = H[(size_t)s2 * HIDDIM + lane];
      float h3 = H[(size_t)s3 * HIDDIM + lane];
      acc = fmaf(e0, h0, acc);
      acc = fmaf(e1, h1, acc);
      acc = fmaf(e2, h2, acc);
      acc = fmaf(e3, h3, acc);
    }
    for (; j < deg; ++j) {
      int   sj = __shfl(s_l, j, 64);
      float ej = __shfl(ex_l, j, 64);
      acc = fmaf(ej, H[(size_t)sj * HIDDIM + lane], acc);
    }
  } else {
    // ---- generic chunked path (deg > 64, statistically rare) ----
    float lmax = -INFINITY, aesum = 0.f;
    for (int base = 0; base < deg; base += 64) {
      int i = base + lane;
      if (i < deg) {
        float4 ed = EDG[off + i];
        int s = __float_as_int(ed.x);
        float ae = (SEL == 0) ? ed.y : ed.z;
        float lg = leaky(alpha_s[s] + ad + ae);
        lmax = fmaxf(lmax, lg);
        aesum += ae;
      }
    }
#pragma unroll
    for (int d = 32; d > 0; d >>= 1) {
      lmax = fmaxf(lmax, __shfl_xor(lmax, d, 64));
      aesum += __shfl_xor(aesum, d, 64);
    }
    float self_ae = aesum / (float)deg;
    float slg = leaky(asn + ad + self_ae);
    float m = fmaxf(lmax, slg);
    float exs = __expf(slg - m);
    float dsum = 0.f;
    acc = exs * H[(size_t)node * HIDDIM + lane];
    for (int base = 0; base < deg; base += 64) {
      int i = base + lane;
      int cnt = min(64, deg - base);
      float4 ed = make_float4(0.f, 0.f, 0.f, 0.f);
      if (i < deg) ed = EDG[off + i];
      int   s_l  = __float_as_int(ed.x);
      float ae_l = (SEL == 0) ? ed.y : ed.z;
      float ex_l = (lane < cnt) ? __expf(leaky(alpha_s[s_l] + ad + ae_l) - m) : 0.f;
      dsum += ex_l;
      for (int j = 0; j < cnt; ++j) {
        int   sj = __shfl(s_l, j, 64);
        float ej = __shfl(ex_l, j, 64);
        acc = fmaf(ej, H[(size_t)sj * HIDDIM + lane], acc);
      }
    }
#pragma unroll
    for (int d = 32; d > 0; d >>= 1) dsum += __shfl_xor(dsum, d, 64);
    denom = dsum + exs;
  }

  float res = acc / denom + bias[lane];
  res = (res > 0.f) ? res : (__expf(res) - 1.f);  // ELU
  if (!FINAL) {
    out[(size_t)node * HIDDIM + lane] = res;
  } else {
    float s1 = res * fc_w[lane];
#pragma unroll
    for (int d = 32; d > 0; d >>= 1) s1 += __shfl_xor(s1, d, 64);
    if (lane == 0) out[node] = s1 + fc_b[0];
  }
}

extern "C" void kernel_launch(void* const* d_in, const int* in_sizes, int n_in,
                              void* d_out, int out_size, void* d_ws, size_t ws_size,
                              hipStream_t stream) {
  const float* x    = (const float*)d_in[0];
  const int*   ei   = (const int*)d_in[1];
  const float* attr = (const float*)d_in[2];
  const float* W1   = (const float*)d_in[3];
  const float* as1  = (const float*)d_in[4];
  const float* ad1  = (const float*)d_in[5];
  const float* We1  = (const float*)d_in[6];
  const float* ae1  = (const float*)d_in[7];
  const float* b1   = (const float*)d_in[8];
  const float* W2   = (const float*)d_in[9];
  const float* as2  = (const float*)d_in[10];
  const float* ad2  = (const float*)d_in[11];
  const float* We2  = (const float*)d_in[12];
  const float* ae2  = (const float*)d_in[13];
  const float* b2   = (const float*)d_in[14];
  const float* fcw  = (const float*)d_in[15];
  const float* fcb  = (const float*)d_in[16];

  const int N = in_sizes[0] / HIDDIM;       // 100000 (F_NODE == 64)
  const int E = in_sizes[1] / 2;            // 3200000

  // workspace bump allocator (256B aligned)
  char* p = (char*)d_ws;
  auto alloc = [&](size_t bytes) -> void* {
    void* r = (void*)p;
    p += (bytes + 255) & ~(size_t)255;
    return r;
  };
  float*  c        = (float*)alloc(32 * sizeof(float));
  int*    deg      = (int*)alloc((size_t)N * 4);
  int*    offsets  = (int*)alloc(((size_t)N + 1) * 4);
  int*    cursor   = (int*)alloc((size_t)N * 4);
  int*    chunkSum = (int*)alloc(128 * 4);
  int*    chunkOff = (int*)alloc(128 * 4);
  float4* EDG      = (float4*)alloc((size_t)E * 16);
  float*  alpha_s  = (float*)alloc((size_t)N * 4);
  float*  alpha_d  = (float*)alloc((size_t)N * 4);
  float*  H        = (float*)alloc((size_t)N * HIDDIM * 4);
  float*  X2       = (float*)alloc((size_t)N * HIDDIM * 4);

  const int* srcp = ei;
  const int* dstp = ei + E;

  hipMemsetAsync(deg, 0, (size_t)N * 4, stream);
  hipMemsetAsync(cursor, 0, (size_t)N * 4, stream);

  compute_c_kernel<<<1, 64, 0, stream>>>(We1, ae1, We2, ae2, c);

  int ethreads = 256;
  int eblocks = (E + ethreads - 1) / ethreads;
  deg_kernel<<<eblocks, ethreads, 0, stream>>>(dstp, deg, E);

  int nchunks = (N + SCAN_CHUNK - 1) / SCAN_CHUNK;   // 98
  chunk_sum_kernel<<<nchunks, 256, 0, stream>>>(deg, chunkSum, N);
  scan_chunks_kernel<<<1, 128, 0, stream>>>(chunkSum, chunkOff, nchunks);
  scan_apply_kernel<<<nchunks, 256, 0, stream>>>(deg, chunkOff, offsets, N, E);

  scatter_kernel<<<eblocks, ethreads, 0, stream>>>(srcp, dstp, attr, c, offsets, cursor,
                                                   EDG, E);

  int aggBlocks = (N + 3) / 4;   // 4 waves (nodes) per 256-thread block

  // layer 1
  gemm_alpha_kernel<<<2048, 256, 0, stream>>>(x, W1, as1, ad1, H, alpha_s, alpha_d, N);
  aggregate_kernel<false, 0><<<aggBlocks, 256, 0, stream>>>(H, alpha_s, alpha_d, EDG,
                                                            offsets, b1, nullptr, nullptr, X2, N);
  // layer 2 + fused FC
  gemm_alpha_kernel<<<2048, 256, 0, stream>>>(X2, W2, as2, ad2, H, alpha_s, alpha_d, N);
  aggregate_kernel<true, 0 + 1><<<aggBlocks, 256, 0, stream>>>(H, alpha_s, alpha_d, EDG,
                                                               offsets, b2, fcw, fcb, (float*)d_out, N);
}